// Round 15
// baseline (57.987 us; speedup 1.0000x reference)
//
#include <hip/hip_runtime.h>
#include <hip/hip_bf16.h>
#include <math.h>

#define BN 8192
#define DK 128
#define NSPLIT 16
#define JR (BN / NSPLIT)    // 512 cols per split
#define NSUB (JR / 32)      // 16 subtiles of 32 cols
#define MARGIN_F 1.0f

// ---------------- workspace layout (float-slot offsets from d_ws) -------------
// Eb  : bf16 8192x128 (B-side)            = 2MB
// EbS : bf16 8192x128 scaled by -128 (A)  = 2MB
// sq64: f32 [BN]  64*sum(x^2)
// posV/negV: f32 [NSPLIT][BN] mined key values (64*(sq_j-2dot))
// red : ull sum + uint counter (16B)
#define OFF_EBS  524288
#define OFF_SQ   1048576
#define OFF_POSV (OFF_SQ + BN)
#define OFF_NEGV (OFF_POSV + NSPLIT * BN)
#define OFF_RED  (OFF_NEGV + NSPLIT * BN)

typedef __attribute__((ext_vector_type(8))) short bf16x8;
typedef __attribute__((ext_vector_type(4))) float f32x4;

__device__ __forceinline__ unsigned short f2bf(float f) {
    __hip_bfloat16 h = __float2bfloat16(f);
    return *reinterpret_cast<unsigned short*>(&h);
}

// ---------------- prep: bf16 tables + 64*rowsq + zero the reduction cell ------
__global__ __launch_bounds__(256) void k_prep(const float* __restrict__ emb,
                                              unsigned short* __restrict__ Eb,
                                              unsigned short* __restrict__ EbS,
                                              float* __restrict__ sq64,
                                              unsigned long long* __restrict__ red) {
    if (blockIdx.x == 0 && threadIdx.x == 0) {   // replaces hipMemsetAsync
        red[0] = 0ULL;
        red[1] = 0ULL;
    }
    int row  = blockIdx.x * 4 + (threadIdx.x >> 6);
    int lane = threadIdx.x & 63;
    float2 v = ((const float2*)(emb + (size_t)row * DK))[lane];
    ushort2 o;  o.x  = f2bf(v.x);           o.y  = f2bf(v.y);
    ushort2 os; os.x = f2bf(v.x * -128.0f); os.y = f2bf(v.y * -128.0f);
    ((ushort2*)(Eb  + (size_t)row * DK))[lane] = o;
    ((ushort2*)(EbS + (size_t)row * DK))[lane] = os;
    float s = v.x * v.x + v.y * v.y;
    #pragma unroll
    for (int m = 32; m; m >>= 1) s += __shfl_xor(s, m);
    if (lane == 0) sq64[row] = 64.0f * s;
}

// ---------------- fused MFMA Gram + batch-hard VALUE mining (no LDS) ----------
// 512 blocks = 32 igroups x 16 splits; block = 4 fully-independent waves
// (no __shared__, no barriers). Wave owns 64 i-rows x the split's 512 cols,
// processed as 16 subtiles of 32 cols. B-fragments + column metadata are
// register-prefetched ONE SUBTILE AHEAD (ping-pong sets) straight from L2:
// compute/subtile ~480cyc >> ~200cyc L2 latency -> latency fully hidden,
// no barrier/vmcnt drains (r14's LDS path had 4 per wave), no ds_reads.
// acc init = 64*sq_j; MFMA adds (-128 x_i)·x_j => acc = 64*(sq_j-2dot) = key.
// Self-pair: key_self = -64*sq_i << any real positive key -> never wins max.
// VGPR ~190 < 256 keeps the (empirical) 2 waves/SIMD; do NOT add min-waves
// bounds (r6/r8 spill cliff) or grow state past ~256 (r13 collapse).
__global__ __launch_bounds__(256)
void k_mine10(const unsigned short* __restrict__ Eb,
              const unsigned short* __restrict__ EbS,
              const float* __restrict__ sq64,
              const int* __restrict__ tgt,
              float* __restrict__ posV, float* __restrict__ negV) {
    const int tid = threadIdx.x;
    const int w   = tid >> 6;
    const int l   = tid & 63;
    const int lh  = l >> 4;
    const int tx  = l & 15;
    const int igroup = blockIdx.x >> 4;   // 0..31
    const int split  = blockIdx.x & 15;   // 0..15
    const int i0w = igroup * 256 + w * 64;
    const int jb  = split * JR;
    const char* EbB = (const char*)Eb;

    // A fragments (64 rows per wave) from the -128-scaled table
    bf16x8 A[4][4];
    #pragma unroll
    for (int mi = 0; mi < 4; ++mi) {
        const char* rp = (const char*)EbS + (size_t)(i0w + mi * 16 + tx) * 256 + lh * 16;
        #pragma unroll
        for (int ks = 0; ks < 4; ++ks)
            A[mi][ks] = *(const bf16x8*)(rp + ks * 64);
    }

    // per-lane i-row targets
    int t8[16];
    #pragma unroll
    for (int mi = 0; mi < 4; ++mi) {
        int4 q = *(const int4*)(tgt + i0w + mi * 16 + lh * 4);
        t8[mi * 4 + 0] = q.x; t8[mi * 4 + 1] = q.y;
        t8[mi * 4 + 2] = q.z; t8[mi * 4 + 3] = q.w;
    }

    float pp[16], nn[16];
    #pragma unroll
    for (int r = 0; r < 16; ++r) { pp[r] = -INFINITY; nn[r] = INFINITY; }

    // ping-pong B-fragment + metadata sets
    bf16x8 BA[2][4], BB[2][4];
    float sqA[2], sqB[2]; int tjA[2], tjB[2];

    // load subtile s's B frags + col metadata into a set (direct from L2)
    auto loadB = [&](bf16x8 (&Bn)[2][4], float (&sqn)[2], int (&tjn)[2], int s) {
        #pragma unroll
        for (int u = 0; u < 2; ++u) {
            int j = jb + s * 32 + u * 16 + tx;
            const char* bp = EbB + (size_t)j * 256 + lh * 16;
            #pragma unroll
            for (int ks = 0; ks < 4; ++ks)
                Bn[u][ks] = *(const bf16x8*)(bp + ks * 64);
            sqn[u] = sq64[j];
            tjn[u] = tgt[j];
        }
    };

    // compute subtile s from set c while prefetching s+1 into set n
    auto body = [&](bf16x8 (&Bc)[2][4], float (&sqc)[2], int (&tjc)[2],
                    bf16x8 (&Bn)[2][4], float (&sqn)[2], int (&tjn)[2], int s) {
        if (s + 1 < NSUB) loadB(Bn, sqn, tjn, s + 1);

        f32x4 acc[4][2];
        #pragma unroll
        for (int mi = 0; mi < 4; ++mi)
            #pragma unroll
            for (int u = 0; u < 2; ++u) {
                float sv = sqc[u];
                f32x4 a0 = {sv, sv, sv, sv};
                acc[mi][u] = a0;
            }

        __builtin_amdgcn_s_setprio(1);
        #pragma unroll
        for (int ks = 0; ks < 4; ++ks)
            #pragma unroll
            for (int mi = 0; mi < 4; ++mi)
                #pragma unroll
                for (int u = 0; u < 2; ++u)
                    acc[mi][u] = __builtin_amdgcn_mfma_f32_16x16x32_bf16(
                        A[mi][ks], Bc[u][ks], acc[mi][u], 0, 0, 0);
        __builtin_amdgcn_s_setprio(0);

        // value-mining epilogue: acc == 64*(sq_j - 2 dot) == 64*key
        const int tj0 = tjc[0], tj1 = tjc[1];
        #pragma unroll
        for (int mi = 0; mi < 4; ++mi) {
            #pragma unroll
            for (int v = 0; v < 4; ++v) {
                const int r = mi * 4 + v;
                const int trg = t8[r];
                float k0 = acc[mi][0][v];
                float k1 = acc[mi][1][v];
                bool s0 = (tj0 == trg);
                bool s1 = (tj1 == trg);
                float a0 = s0 ? k0 : -INFINITY;
                float b0 = s0 ? INFINITY : k0;
                float a1 = s1 ? k1 : -INFINITY;
                float b1 = s1 ? INFINITY : k1;
                pp[r] = fmaxf(fmaxf(pp[r], a0), a1);   // -> v_max3_f32
                nn[r] = fminf(fminf(nn[r], b0), b1);   // -> v_min3_f32
            }
        }
    };

    loadB(BA, sqA, tjA, 0);
    for (int s = 0; s < NSUB; s += 2) {
        body(BA, sqA, tjA, BB, sqB, tjB, s);
        body(BB, sqB, tjB, BA, sqA, tjA, s + 1);
    }

    // reduce across the 16 tx lanes
    #pragma unroll
    for (int r = 0; r < 16; ++r) {
        float p = pp[r], n = nn[r];
        #pragma unroll
        for (int m = 1; m < 16; m <<= 1) {
            p = fmaxf(p, __shfl_xor(p, m));
            n = fminf(n, __shfl_xor(n, m));
        }
        if (tx == 0) {
            int row = i0w + (r >> 2) * 16 + lh * 4 + (r & 3);
            posV[split * BN + row] = p;
            negV[split * BN + row] = n;
        }
    }
}

// ---------------- combine splits + loss + mean (fused, deterministic) ---------
// 32 blocks x 256 threads, 1 row/thread, streaming loads (no gathers).
// d2 = (key64 + 64*sq_i)/64, clamped >= 0 (matches ref's maximum(d2,0)).
// Block-sum f32 (fixed order) -> 2^-24 fixed-point -> 32 integer atomics
// (commutative-exact) -> last block writes the mean.
__global__ __launch_bounds__(256) void k_finm(const float* __restrict__ sq64,
                                              const float* __restrict__ posV,
                                              const float* __restrict__ negV,
                                              unsigned long long* __restrict__ red,
                                              float* __restrict__ out) {
    int row  = blockIdx.x * 256 + threadIdx.x;
    int lane = threadIdx.x & 63;

    float p = -INFINITY, n = INFINITY;
    #pragma unroll
    for (int s = 0; s < NSPLIT; ++s) {
        p = fmaxf(p, posV[s * BN + row]);
        n = fminf(n, negV[s * BN + row]);
    }
    float s64 = sq64[row];
    float d2p = fmaxf(p + s64, 0.f) * 0.015625f;
    float d2n = fmaxf(n + s64, 0.f) * 0.015625f;
    float lo  = sqrtf(d2p) - sqrtf(d2n) + MARGIN_F;
    lo = lo > 0.f ? lo : 0.f;

    #pragma unroll
    for (int m = 32; m; m >>= 1) lo += __shfl_xor(lo, m);
    __shared__ float part[4];
    if (lane == 0) part[threadIdx.x >> 6] = lo;
    __syncthreads();
    if (threadIdx.x == 0) {
        float bs = part[0] + part[1] + part[2] + part[3];
        atomicAdd(red, (unsigned long long)(bs * 16777216.0f));
        __threadfence();
        unsigned int t = atomicAdd((unsigned int*)(red + 1), 1u);
        if (t == gridDim.x - 1) {
            unsigned long long tot = atomicAdd(red, 0ULL);
            out[0] = (float)((double)tot / 16777216.0 / (double)BN);
        }
    }
}

extern "C" void kernel_launch(void* const* d_in, const int* in_sizes, int n_in,
                              void* d_out, int out_size, void* d_ws, size_t ws_size,
                              hipStream_t stream) {
    const float* emb = (const float*)d_in[0];
    const int*   tgt = (const int*)d_in[1];
    float* out = (float*)d_out;

    float* wsf = (float*)d_ws;
    unsigned short* Eb  = (unsigned short*)wsf;
    unsigned short* EbS = (unsigned short*)(wsf + OFF_EBS);
    float* sq64 = wsf + OFF_SQ;
    float* posV = wsf + OFF_POSV;
    float* negV = wsf + OFF_NEGV;
    unsigned long long* red = (unsigned long long*)(wsf + OFF_RED);

    k_prep<<<BN / 4, 256, 0, stream>>>(emb, Eb, EbS, sq64, red);
    k_mine10<<<(BN / 256) * NSPLIT, 256, 0, stream>>>(Eb, EbS, sq64, tgt, posV, negV);
    k_finm<<<BN / 256, 256, 0, stream>>>(sq64, posV, negV, red, out);
}

// Round 16
// 40.743 us; speedup vs baseline: 1.4232x; 1.4232x over previous
//
#include <hip/hip_runtime.h>
#include <hip/hip_bf16.h>
#include <math.h>

#define BN 8192
#define DK 128
#define NSPLIT 16
#define JR (BN / NSPLIT)    // 512 cols per split
#define NG (JR / 128)       // 4 intervals of 128 cols
#define MARGIN_F 1.0f

// ---------------- workspace layout (float-slot offsets from d_ws) -------------
// Eb  : bf16 8192x128 (B-side)            = 2MB
// EbS : bf16 8192x128 scaled by -128 (A)  = 2MB
// sq64: f32 [BN]  64*sum(x^2)
// posV/negV: f32 [NSPLIT][BN] mined key values (64*(sq_j-2dot))
// red : ull sum + uint counter (16B)
#define OFF_EBS  524288
#define OFF_SQ   1048576
#define OFF_POSV (OFF_SQ + BN)
#define OFF_NEGV (OFF_POSV + NSPLIT * BN)
#define OFF_RED  (OFF_NEGV + NSPLIT * BN)

typedef __attribute__((ext_vector_type(8))) short bf16x8;
typedef __attribute__((ext_vector_type(4))) float f32x4;

__device__ __forceinline__ unsigned short f2bf(float f) {
    __hip_bfloat16 h = __float2bfloat16(f);
    return *reinterpret_cast<unsigned short*>(&h);
}

__device__ __forceinline__ void gload_lds16(const void* g, void* s) {
    __builtin_amdgcn_global_load_lds(
        (const __attribute__((address_space(1))) void*)g,
        (__attribute__((address_space(3))) void*)s, 16, 0, 0);
}

// ---------------- prep: bf16 tables + 64*rowsq + zero the reduction cell ------
__global__ __launch_bounds__(256) void k_prep(const float* __restrict__ emb,
                                              unsigned short* __restrict__ Eb,
                                              unsigned short* __restrict__ EbS,
                                              float* __restrict__ sq64,
                                              unsigned long long* __restrict__ red) {
    if (blockIdx.x == 0 && threadIdx.x == 0) {   // replaces hipMemsetAsync
        red[0] = 0ULL;
        red[1] = 0ULL;
    }
    int row  = blockIdx.x * 4 + (threadIdx.x >> 6);
    int lane = threadIdx.x & 63;
    float2 v = ((const float2*)(emb + (size_t)row * DK))[lane];
    ushort2 o;  o.x  = f2bf(v.x);           o.y  = f2bf(v.y);
    ushort2 os; os.x = f2bf(v.x * -128.0f); os.y = f2bf(v.y * -128.0f);
    ((ushort2*)(Eb  + (size_t)row * DK))[lane] = o;
    ((ushort2*)(EbS + (size_t)row * DK))[lane] = os;
    float s = v.x * v.x + v.y * v.y;
    #pragma unroll
    for (int m = 32; m; m >>= 1) s += __shfl_xor(s, m);
    if (lane == 0) sq64[row] = 64.0f * s;
}

// ---------------- fused MFMA Gram + batch-hard VALUE mining -------------------
// Round-14 configuration — the empirical optimum of this search:
// 512 blocks = 32 igroups x 16 splits; block = 4 waves x 64 i-rows covering
// 256 rows x 512 cols; B in 128-col intervals, double-buffered 2x32KB LDS via
// async global_load_lds (zero-VGPR prefetch); 4 barriers/wave.
// Mine the f32 KEY VALUE only (no indices). acc init = 64*sq_j; MFMA adds
// (-128 x_i)·x_j  =>  acc = 64*(sq_j - 2 dot) = 64*key. Epilogue per element:
// cmp + cndmask(-INF/+INF) + v_max3/min3_f32.
// Self-pair: key_self = -64*sq_i << any real positive key -> never wins max.
// Closed dead-ends (measured): min-waves bounds -> 64-VGPR spill cliff (r6/r8);
// NSPLIT=32 supply -> no extra residency at VGPR=128 (r7); symmetric tiles ->
// VGPR 224 occupancy collapse (r13); no-LDS reg-prefetch -> 46.6us (r15, VGPR
// 144, occupancy 9%); barrier halving beyond 4 -> neutral (r11).
__global__ __launch_bounds__(256)
void k_mine8(const unsigned short* __restrict__ Eb,
             const unsigned short* __restrict__ EbS,
             const float* __restrict__ sq64,
             const int* __restrict__ tgt,
             float* __restrict__ posV, float* __restrict__ negV) {
    __shared__ __align__(16) char Blds[2][2][16384];   // [buf][half][16KB]

    const int tid = threadIdx.x;
    const int w   = tid >> 6;
    const int l   = tid & 63;
    const int lh  = l >> 4;
    const int tx  = l & 15;
    const int igroup = blockIdx.x >> 4;   // 0..31
    const int split  = blockIdx.x & 15;   // 0..15
    const int i0w = igroup * 256 + w * 64;
    const int jb  = split * JR;
    const char* EbB = (const char*)Eb;

    // A fragments (64 rows per wave) from the -128-scaled table
    bf16x8 A[4][4];
    #pragma unroll
    for (int mi = 0; mi < 4; ++mi) {
        const char* rp = (const char*)EbS + (size_t)(i0w + mi * 16 + tx) * 256 + lh * 16;
        #pragma unroll
        for (int ks = 0; ks < 4; ++ks)
            A[mi][ks] = *(const bf16x8*)(rp + ks * 64);
    }

    // per-lane i-row targets: t8[mi*4+v] = tgt[i0w + mi*16 + lh*4 + v]
    int t8[16];
    #pragma unroll
    for (int mi = 0; mi < 4; ++mi) {
        int4 q = *(const int4*)(tgt + i0w + mi * 16 + lh * 4);
        t8[mi * 4 + 0] = q.x; t8[mi * 4 + 1] = q.y;
        t8[mi * 4 + 2] = q.z; t8[mi * 4 + 3] = q.w;
    }

    float pp[16], nn[16];
    #pragma unroll
    for (int r = 0; r < 16; ++r) { pp[r] = -INFINITY; nn[r] = INFINITY; }

    // stage one 64-col subtile (16KB), source-preswizzled:
    // LDS[row][c] = Eb[j0+row][c ^ (row&7)], c = 16B chunk; dst linear.
    auto stage64 = [&](char* dst, int jcol0) {
        const char* S = EbB + (size_t)jcol0 * 256;
        #pragma unroll
        for (int q = 0; q < 4; ++q) {
            int f  = tid + 256 * q;           // 0..1023
            int gr = f >> 4;                  // subtile row 0..63
            int sc = (f & 15) ^ (gr & 7);     // swizzled source chunk
            gload_lds16(S + gr * 256 + sc * 16, dst + w * 1024 + q * 4096);
        }
    };

    stage64(Blds[0][0], jb);
    stage64(Blds[0][1], jb + 64);
    __syncthreads();

    for (int g = 0; g < NG; ++g) {
        const int buf = g & 1;
        if (g + 1 < NG) {                       // async prefetch next 128 cols
            stage64(Blds[buf ^ 1][0], jb + (g + 1) * 128);
            stage64(Blds[buf ^ 1][1], jb + (g + 1) * 128 + 64);
        }
        const int j0 = jb + g * 128;

        // per-interval column metadata (hoisted; hides under MFMA)
        float sqv[4][2]; int tjv[4][2];
        #pragma unroll
        for (int s = 0; s < 4; ++s)
            #pragma unroll
            for (int u = 0; u < 2; ++u) {
                int j = j0 + s * 32 + u * 16 + tx;
                sqv[s][u] = sq64[j]; tjv[s][u] = tgt[j];
            }

        #pragma unroll
        for (int s = 0; s < 4; ++s) {           // 32-col subtiles
            f32x4 acc[4][2];
            #pragma unroll
            for (int mi = 0; mi < 4; ++mi)
                #pragma unroll
                for (int u = 0; u < 2; ++u) {
                    float sv = sqv[s][u];
                    f32x4 a0 = {sv, sv, sv, sv};
                    acc[mi][u] = a0;
                }

            const char* base = Blds[buf][s >> 1];
            #pragma unroll
            for (int ks = 0; ks < 4; ++ks) {
                bf16x8 Bf[2];
                #pragma unroll
                for (int u = 0; u < 2; ++u) {
                    int row = (s & 1) * 32 + u * 16 + tx;
                    int c   = (ks * 4 + lh) ^ (row & 7);
                    Bf[u] = *(const bf16x8*)(base + row * 256 + c * 16);
                }
                __builtin_amdgcn_s_setprio(1);
                #pragma unroll
                for (int mi = 0; mi < 4; ++mi)
                    #pragma unroll
                    for (int u = 0; u < 2; ++u)
                        acc[mi][u] = __builtin_amdgcn_mfma_f32_16x16x32_bf16(
                            A[mi][ks], Bf[u], acc[mi][u], 0, 0, 0);
                __builtin_amdgcn_s_setprio(0);
            }

            // value-mining epilogue: acc == 64*(sq_j - 2 dot) == 64*key
            const int tj0 = tjv[s][0], tj1 = tjv[s][1];
            #pragma unroll
            for (int mi = 0; mi < 4; ++mi) {
                #pragma unroll
                for (int v = 0; v < 4; ++v) {
                    const int r = mi * 4 + v;
                    const int trg = t8[r];
                    float k0 = acc[mi][0][v];
                    float k1 = acc[mi][1][v];
                    bool s0 = (tj0 == trg);
                    bool s1 = (tj1 == trg);
                    float a0 = s0 ? k0 : -INFINITY;
                    float b0 = s0 ? INFINITY : k0;
                    float a1 = s1 ? k1 : -INFINITY;
                    float b1 = s1 ? INFINITY : k1;
                    pp[r] = fmaxf(fmaxf(pp[r], a0), a1);   // -> v_max3_f32
                    nn[r] = fminf(fminf(nn[r], b0), b1);   // -> v_min3_f32
                }
            }
        }

        __syncthreads();   // all waves done reading buf; prefetch complete
    }

    // reduce across the 16 tx lanes
    #pragma unroll
    for (int r = 0; r < 16; ++r) {
        float p = pp[r], n = nn[r];
        #pragma unroll
        for (int m = 1; m < 16; m <<= 1) {
            p = fmaxf(p, __shfl_xor(p, m));
            n = fminf(n, __shfl_xor(n, m));
        }
        if (tx == 0) {
            int row = i0w + (r >> 2) * 16 + lh * 4 + (r & 3);
            posV[split * BN + row] = p;
            negV[split * BN + row] = n;
        }
    }
}

// ---------------- combine splits + loss + mean (fused, deterministic) ---------
// 32 blocks x 256 threads, 1 row/thread, streaming loads (no gathers).
// d2 = (key64 + 64*sq_i)/64, clamped >= 0 (matches ref's maximum(d2,0)).
// Block-sum f32 (fixed order) -> 2^-24 fixed-point -> 32 integer atomics
// (commutative-exact) -> last block writes the mean.
__global__ __launch_bounds__(256) void k_finm(const float* __restrict__ sq64,
                                              const float* __restrict__ posV,
                                              const float* __restrict__ negV,
                                              unsigned long long* __restrict__ red,
                                              float* __restrict__ out) {
    int row  = blockIdx.x * 256 + threadIdx.x;
    int lane = threadIdx.x & 63;

    float p = -INFINITY, n = INFINITY;
    #pragma unroll
    for (int s = 0; s < NSPLIT; ++s) {
        p = fmaxf(p, posV[s * BN + row]);
        n = fminf(n, negV[s * BN + row]);
    }
    float s64 = sq64[row];
    float d2p = fmaxf(p + s64, 0.f) * 0.015625f;
    float d2n = fmaxf(n + s64, 0.f) * 0.015625f;
    float lo  = sqrtf(d2p) - sqrtf(d2n) + MARGIN_F;
    lo = lo > 0.f ? lo : 0.f;

    #pragma unroll
    for (int m = 32; m; m >>= 1) lo += __shfl_xor(lo, m);
    __shared__ float part[4];
    if (lane == 0) part[threadIdx.x >> 6] = lo;
    __syncthreads();
    if (threadIdx.x == 0) {
        float bs = part[0] + part[1] + part[2] + part[3];
        atomicAdd(red, (unsigned long long)(bs * 16777216.0f));
        __threadfence();
        unsigned int t = atomicAdd((unsigned int*)(red + 1), 1u);
        if (t == gridDim.x - 1) {
            unsigned long long tot = atomicAdd(red, 0ULL);
            out[0] = (float)((double)tot / 16777216.0 / (double)BN);
        }
    }
}

extern "C" void kernel_launch(void* const* d_in, const int* in_sizes, int n_in,
                              void* d_out, int out_size, void* d_ws, size_t ws_size,
                              hipStream_t stream) {
    const float* emb = (const float*)d_in[0];
    const int*   tgt = (const int*)d_in[1];
    float* out = (float*)d_out;

    float* wsf = (float*)d_ws;
    unsigned short* Eb  = (unsigned short*)wsf;
    unsigned short* EbS = (unsigned short*)(wsf + OFF_EBS);
    float* sq64 = wsf + OFF_SQ;
    float* posV = wsf + OFF_POSV;
    float* negV = wsf + OFF_NEGV;
    unsigned long long* red = (unsigned long long*)(wsf + OFF_RED);

    k_prep<<<BN / 4, 256, 0, stream>>>(emb, Eb, EbS, sq64, red);
    k_mine8<<<(BN / 256) * NSPLIT, 256, 0, stream>>>(Eb, EbS, sq64, tgt, posV, negV);
    k_finm<<<BN / 256, 256, 0, stream>>>(sq64, posV, negV, red, out);
}